// Round 1
// baseline (1225.268 us; speedup 1.0000x reference)
//
#include <hip/hip_runtime.h>
#include <cstdint>

// Problem constants
#define T3   1536   // (NGRAM+1)*TM
#define TMQ  512    // TM
#define BB   4      // batch
#define EE   1024   // embed
#define HH   16     // heads
#define HD   64     // head dim
#define NBK  32     // buckets
#define BHH  64     // B*H

// ---------------------------------------------------------------------------
// GEMM (NT): C = (A @ W^T + bias) * scale
// A: (M,1024) row-major, W: (N,1024) row-major, M multiple of 64, N multiple of 64.
// BM=BN=64, BK=32, 256 threads, 4x4 micro-tile, transposed LDS tiles for float4 reads.
// MODE 0: write QKV layout (BH, T3, hd)   out[(bh*T3 + t3)*64 + d]
// MODE 1: write vals layout (stream, BH, TM, NB)
// MODE 2: plain row-major (M, 1024)
// ---------------------------------------------------------------------------
template<int MODE>
__global__ __launch_bounds__(256) void gemm_nt(
    const float* __restrict__ A, const float* __restrict__ W,
    const float* __restrict__ bias, float* __restrict__ out, float scale)
{
    __shared__ float As[32][68];   // [k][m], +4 pad keeps float4 alignment, breaks conflicts
    __shared__ float Ws[32][68];   // [k][n]
    const int tid = threadIdx.x;
    const int tx = tid & 15, ty = tid >> 4;
    const int m0 = blockIdx.y * 64, n0 = blockIdx.x * 64;

    float acc[4][4] = {};

    const int r  = tid >> 2;   // loader row 0..63
    const int kq = tid & 3;    // loader k-octet 0..3
    const float* Ap = A + (size_t)(m0 + r) * EE + kq * 8;
    const float* Wp = W + (size_t)(n0 + r) * EE + kq * 8;

    for (int k0 = 0; k0 < EE; k0 += 32) {
        const float4 a0 = *(const float4*)(Ap + k0);
        const float4 a1 = *(const float4*)(Ap + k0 + 4);
        const float4 w0 = *(const float4*)(Wp + k0);
        const float4 w1 = *(const float4*)(Wp + k0 + 4);
        __syncthreads();   // previous iteration's reads done before overwrite
        const int kb = kq * 8;
        As[kb+0][r]=a0.x; As[kb+1][r]=a0.y; As[kb+2][r]=a0.z; As[kb+3][r]=a0.w;
        As[kb+4][r]=a1.x; As[kb+5][r]=a1.y; As[kb+6][r]=a1.z; As[kb+7][r]=a1.w;
        Ws[kb+0][r]=w0.x; Ws[kb+1][r]=w0.y; Ws[kb+2][r]=w0.z; Ws[kb+3][r]=w0.w;
        Ws[kb+4][r]=w1.x; Ws[kb+5][r]=w1.y; Ws[kb+6][r]=w1.z; Ws[kb+7][r]=w1.w;
        __syncthreads();
        #pragma unroll
        for (int kk = 0; kk < 32; ++kk) {
            const float4 av = *(const float4*)&As[kk][ty*4];
            const float4 wv = *(const float4*)&Ws[kk][tx*4];
            const float ar[4] = {av.x, av.y, av.z, av.w};
            const float wr[4] = {wv.x, wv.y, wv.z, wv.w};
            #pragma unroll
            for (int i = 0; i < 4; ++i) {
                #pragma unroll
                for (int j = 0; j < 4; ++j) acc[i][j] += ar[i] * wr[j];
            }
        }
    }

    const int nbase = n0 + tx * 4;
    float bs[4];
    #pragma unroll
    for (int j = 0; j < 4; ++j) bs[j] = bias[nbase + j];

    #pragma unroll
    for (int i = 0; i < 4; ++i) {
        const int m = m0 + ty * 4 + i;
        float c[4];
        #pragma unroll
        for (int j = 0; j < 4; ++j) c[j] = (acc[i][j] + bs[j]) * scale;

        if (MODE == 0) {
            // hidden row m = t3*B + b ; col n -> (h = n/64 const per block, d = n%64)
            const int t3 = m >> 2, b = m & 3;
            const int h  = n0 >> 6;            // BN=64 aligns with head boundary
            const int bh = b * HH + h;
            float4 c4; c4.x=c[0]; c4.y=c[1]; c4.z=c[2]; c4.w=c[3];
            *(float4*)(out + ((size_t)bh * T3 + t3) * HD + tx * 4) = c4;
        } else if (MODE == 1) {
            // vals[s][bh][tm][nb] = raw[b][t3][nb*16+h]
            const int t3 = m >> 2, b = m & 3;
            const int st = t3 >> 9, tm = t3 & 511;
            #pragma unroll
            for (int j = 0; j < 4; ++j) {
                const int n = nbase + j;
                const int nb = n >> 4, h = n & 15;
                out[(((size_t)st * BHH + b * HH + h) * TMQ + tm) * NBK + nb] = c[j];
            }
        } else {
            float4 c4; c4.x=c[0]; c4.y=c[1]; c4.z=c[2]; c4.w=c[3];
            *(float4*)(out + (size_t)m * EE + nbase) = c4;
        }
    }
}

// ---------------------------------------------------------------------------
// Fused flash-style attention (fp32), one block = (stream s, head bh, 64 q-rows).
// Streams: s=0 main (512 keys), s=1,2 ngram (1024 keys: main keys ++ stream-s keys).
// Per 64-key chunk: S = Q*K^T (4x4 micro GEMM) + vals[bucket] gather + mask,
// online softmax (16-lane shfl row reduce), P through LDS, O += P*V (4x4 micro).
// ---------------------------------------------------------------------------
__global__ __launch_bounds__(256) void attn_fused(
    const float* __restrict__ q, const float* __restrict__ k,
    const float* __restrict__ v, const float* __restrict__ vals,
    const float* __restrict__ self_mask, const float* __restrict__ ngram_mask,
    const int* __restrict__ ibm, const int* __restrict__ ibr,
    float* __restrict__ attn_pre)
{
    __shared__ float Qs[64][68];       // [d][row] transposed
    __shared__ float KVs[64][68];      // K phase: [d][key] ; V phase: [key][d]
    __shared__ float Ps[64][68];       // [row][key]
    __shared__ float vals_s[64][NBK];  // per-row bucket logits

    const int bid = blockIdx.x;
    int s, bh, qt;
    if (bid < 512) { s = 0; bh = bid >> 3; qt = bid & 7; }
    else { const int rr = bid - 512; s = 1 + (rr >> 9); bh = (rr >> 3) & 63; qt = rr & 7; }
    const int b = bh >> 4, h = bh & 15;
    const int tid = threadIdx.x;
    const int tx = tid & 15, ty = tid >> 4;
    const int lr = tid >> 2, lq = tid & 3;   // loader row / quad

    // ---- stage Q tile (transposed) + vals rows ----
    {
        const float* qp = q + ((size_t)bh * T3 + s * TMQ + qt * 64 + lr) * HD;
        #pragma unroll
        for (int rep = 0; rep < 4; ++rep) {
            const int qd = lq + rep * 4;
            const float4 t4 = *(const float4*)(qp + qd * 4);
            Qs[qd*4+0][lr]=t4.x; Qs[qd*4+1][lr]=t4.y; Qs[qd*4+2][lr]=t4.z; Qs[qd*4+3][lr]=t4.w;
        }
        const float* vp = vals + (((size_t)s * BHH + bh) * TMQ + qt * 64) * NBK;
        #pragma unroll
        for (int rep = 0; rep < 2; ++rep) {
            const int idx4 = tid + rep * 256;
            const int rrow = idx4 >> 3, qq = idx4 & 7;
            *(float4*)&vals_s[rrow][qq*4] = *(const float4*)(vp + rrow*NBK + qq*4);
        }
    }

    float m_i[4], l_i[4], o[4][4];
    #pragma unroll
    for (int i = 0; i < 4; ++i) {
        m_i[i] = -1e30f; l_i[i] = 0.f;
        o[i][0]=0.f; o[i][1]=0.f; o[i][2]=0.f; o[i][3]=0.f;
    }

    const int nch = (s == 0) ? 8 : 16;
    for (int c = 0; c < nch; ++c) {
        const int jg0 = c * 64;
        // ---- K chunk -> KVs[d][key] (transposed) ----
        {
            const int jg = jg0 + lr;
            const int t3k = (jg < TMQ) ? jg : (s * TMQ + jg - TMQ);
            const float* kp = k + ((size_t)bh * T3 + t3k) * HD;
            #pragma unroll
            for (int rep = 0; rep < 4; ++rep) {
                const int qd = lq + rep * 4;
                const float4 t4 = *(const float4*)(kp + qd * 4);
                KVs[qd*4+0][lr]=t4.x; KVs[qd*4+1][lr]=t4.y; KVs[qd*4+2][lr]=t4.z; KVs[qd*4+3][lr]=t4.w;
            }
        }
        __syncthreads();

        // ---- scores: 4x4 micro GEMM over d ----
        float sc[4][4] = {};
        #pragma unroll 8
        for (int d = 0; d < 64; ++d) {
            const float4 qa = *(const float4*)&Qs[d][ty*4];
            const float4 kb = *(const float4*)&KVs[d][tx*4];
            const float qr[4] = {qa.x,qa.y,qa.z,qa.w};
            const float kr[4] = {kb.x,kb.y,kb.z,kb.w};
            #pragma unroll
            for (int i = 0; i < 4; ++i) {
                #pragma unroll
                for (int j = 0; j < 4; ++j) sc[i][j] += qr[i] * kr[j];
            }
        }

        // ---- epilogue: bucket-gathered rel logits + additive mask ----
        #pragma unroll
        for (int i = 0; i < 4; ++i) {
            const int tl = ty*4 + i;
            const int t  = qt*64 + tl;
            #pragma unroll
            for (int j = 0; j < 4; ++j) {
                const int jj = jg0 + tx*4 + j;
                int idx; float msk;
                if (s == 0) {
                    idx = ibm[((size_t)b * TMQ + t) * TMQ + jj];
                    msk = self_mask[(size_t)t * TMQ + jj];
                } else {
                    idx = ibr[((size_t)b * TMQ + t) * (2*TMQ) + jj];
                    msk = ngram_mask[((size_t)(s-1) * TMQ + t) * (2*TMQ) + jj];
                }
                sc[i][j] += vals_s[tl][idx] + msk;
            }
        }

        // ---- online softmax (reduce over 16-lane tx group) + stage P ----
        #pragma unroll
        for (int i = 0; i < 4; ++i) {
            const int tl = ty*4 + i;
            float rm = fmaxf(fmaxf(sc[i][0], sc[i][1]), fmaxf(sc[i][2], sc[i][3]));
            rm = fmaxf(rm, __shfl_xor(rm, 1));
            rm = fmaxf(rm, __shfl_xor(rm, 2));
            rm = fmaxf(rm, __shfl_xor(rm, 4));
            rm = fmaxf(rm, __shfl_xor(rm, 8));
            const float mn   = fmaxf(m_i[i], rm);
            const float corr = __expf(m_i[i] - mn);
            float p[4];
            #pragma unroll
            for (int j = 0; j < 4; ++j) p[j] = __expf(sc[i][j] - mn);
            float rs = p[0] + p[1] + p[2] + p[3];
            rs += __shfl_xor(rs, 1);
            rs += __shfl_xor(rs, 2);
            rs += __shfl_xor(rs, 4);
            rs += __shfl_xor(rs, 8);
            l_i[i] = l_i[i] * corr + rs;
            m_i[i] = mn;
            #pragma unroll
            for (int j = 0; j < 4; ++j) o[i][j] *= corr;
            float4 p4; p4.x=p[0]; p4.y=p[1]; p4.z=p[2]; p4.w=p[3];
            *(float4*)&Ps[tl][tx*4] = p4;
        }
        __syncthreads();   // P visible; all score-phase KVs reads done

        // ---- V chunk -> KVs[key][d] ----
        {
            const int jg = jg0 + lr;
            const int t3k = (jg < TMQ) ? jg : (s * TMQ + jg - TMQ);
            const float* vp2 = v + ((size_t)bh * T3 + t3k) * HD;
            #pragma unroll
            for (int rep = 0; rep < 4; ++rep) {
                const int qd = lq + rep * 4;
                *(float4*)&KVs[lr][qd*4] = *(const float4*)(vp2 + qd * 4);
            }
        }
        __syncthreads();

        // ---- O += P * V (4x4 micro over 64 keys) ----
        #pragma unroll 4
        for (int j4 = 0; j4 < 16; ++j4) {
            const float4 p0 = *(const float4*)&Ps[ty*4+0][j4*4];
            const float4 p1 = *(const float4*)&Ps[ty*4+1][j4*4];
            const float4 p2 = *(const float4*)&Ps[ty*4+2][j4*4];
            const float4 p3 = *(const float4*)&Ps[ty*4+3][j4*4];
            const float pr[4][4] = {{p0.x,p0.y,p0.z,p0.w},
                                    {p1.x,p1.y,p1.z,p1.w},
                                    {p2.x,p2.y,p2.z,p2.w},
                                    {p3.x,p3.y,p3.z,p3.w}};
            #pragma unroll
            for (int u = 0; u < 4; ++u) {
                const float4 vv = *(const float4*)&KVs[j4*4+u][tx*4];
                #pragma unroll
                for (int i = 0; i < 4; ++i) {
                    o[i][0] += pr[i][u] * vv.x;
                    o[i][1] += pr[i][u] * vv.y;
                    o[i][2] += pr[i][u] * vv.z;
                    o[i][3] += pr[i][u] * vv.w;
                }
            }
        }
        __syncthreads();   // PV done before next chunk overwrites KVs/Ps
    }

    // ---- normalize + write to attn_pre (T3, B, E) ----
    #pragma unroll
    for (int i = 0; i < 4; ++i) {
        const float inv = 1.0f / l_i[i];
        const int t = qt*64 + ty*4 + i;
        float4 res;
        res.x = o[i][0]*inv; res.y = o[i][1]*inv; res.z = o[i][2]*inv; res.w = o[i][3]*inv;
        *(float4*)(attn_pre + (((size_t)(s * TMQ + t)) * BB + b) * EE + h * HD + tx * 4) = res;
    }
}

// ---------------------------------------------------------------------------
// Launcher. Workspace (floats):
//   q: 6291456 | k: 6291456 | v: 6291456 | vals: 3145728 | attn_pre: 6291456
//   total = 28,311,552 floats = 113.2 MB
// ---------------------------------------------------------------------------
extern "C" void kernel_launch(void* const* d_in, const int* in_sizes, int n_in,
                              void* d_out, int out_size, void* d_ws, size_t ws_size,
                              hipStream_t stream)
{
    const float* hs    = (const float*)d_in[0];
    const float* smask = (const float*)d_in[1];
    const float* nmask = (const float*)d_in[2];
    const int*   ibm   = (const int*)d_in[3];
    const int*   ibr   = (const int*)d_in[4];
    const float* Wq = (const float*)d_in[5];
    const float* bq = (const float*)d_in[6];
    const float* Wk = (const float*)d_in[7];
    const float* bk = (const float*)d_in[8];
    const float* Wv = (const float*)d_in[9];
    const float* bv = (const float*)d_in[10];
    const float* Wo = (const float*)d_in[11];
    const float* bo = (const float*)d_in[12];
    const float* Wr = (const float*)d_in[13];
    const float* br = (const float*)d_in[14];
    float* out = (float*)d_out;
    float* ws  = (float*)d_ws;

    float* qw    = ws;
    float* kw    = qw + (size_t)BHH * T3 * HD;
    float* vw    = kw + (size_t)BHH * T3 * HD;
    float* valsw = vw + (size_t)BHH * T3 * HD;
    float* apre  = valsw + (size_t)3 * BHH * TMQ * NBK;

    dim3 blk(256);
    // projections: q pre-scaled by hd^-0.5 = 0.125 (applied to (xW+b) as in ref)
    gemm_nt<0><<<dim3(16, 96), blk, 0, stream>>>(hs, Wq, bq, qw, 0.125f);
    gemm_nt<0><<<dim3(16, 96), blk, 0, stream>>>(hs, Wk, bk, kw, 1.0f);
    gemm_nt<0><<<dim3(16, 96), blk, 0, stream>>>(hs, Wv, bv, vw, 1.0f);
    gemm_nt<1><<<dim3(8,  96), blk, 0, stream>>>(hs, Wr, br, valsw, 1.0f);
    // fused attention: 512 main blocks + 1024 ngram blocks
    attn_fused<<<dim3(1536), blk, 0, stream>>>(qw, kw, vw, valsw, smask, nmask, ibm, ibr, apre);
    // output projection
    gemm_nt<2><<<dim3(16, 96), blk, 0, stream>>>(apre, Wo, bo, out, 1.0f);
}

// Round 2
// 511.125 us; speedup vs baseline: 2.3972x; 2.3972x over previous
//
#include <hip/hip_runtime.h>
#include <hip/hip_fp16.h>
#include <cstdint>

// Problem constants
#define T3   1536   // (NGRAM+1)*TM
#define TMQ  512    // TM
#define BB   4      // batch
#define EE   1024   // embed
#define HH   16     // heads
#define HD   64     // head dim
#define NBK  32     // buckets
#define BHH  64     // B*H

typedef _Float16 half8 __attribute__((ext_vector_type(8)));
typedef float    f32x4 __attribute__((ext_vector_type(4)));

__device__ inline void gl_lds16(const void* g, void* l) {
    __builtin_amdgcn_global_load_lds(
        (const __attribute__((address_space(1))) uint32_t*)g,
        (__attribute__((address_space(3))) uint32_t*)l, 16, 0, 0);
}

// ---------------------------------------------------------------------------
// fp32 -> fp16 conversion (vectorized, n % 4 == 0)
// ---------------------------------------------------------------------------
__global__ __launch_bounds__(256) void cvt16(
    const float* __restrict__ in, __half* __restrict__ out, int n)
{
    const int i = (blockIdx.x * blockDim.x + threadIdx.x) * 4;
    if (i < n) {
        const float4 v = *(const float4*)(in + i);
        __half2* o = (__half2*)(out + i);
        o[0] = __floats2half2_rn(v.x, v.y);
        o[1] = __floats2half2_rn(v.z, v.w);
    }
}

// ---------------------------------------------------------------------------
// fp16 MFMA GEMM (NT): C = (A @ W^T + bias) * scale, K = 1024.
// m97 structure: BM=BN=128, BK=32, 256 thr (4 waves, 2x2), 16x16x32 MFMA,
// global_load_lds width-16 staging (linear LDS), ds_read_b128 fragments.
// MODE 0: fused QKV -> (BH, T3, hd); blockIdx.x: [0,24), sel = bx>>3
// MODE 1: Wr  -> vals (stream, BH, TM, NB); N=512
// MODE 2: Wo  -> plain row-major (M, 1024)
// ---------------------------------------------------------------------------
template<int MODE>
__global__ __launch_bounds__(256) void gemm16(
    const __half* __restrict__ A,
    const __half* __restrict__ Wa, const __half* __restrict__ Wb, const __half* __restrict__ Wc,
    const float* __restrict__ ba, const float* __restrict__ bb, const float* __restrict__ bc,
    float* __restrict__ oa, float* __restrict__ ob, float* __restrict__ oc)
{
    __shared__ __half As[128 * 32];   // [row][k] row-major, 64 B per row
    __shared__ __half Bs[128 * 32];

    const int tid  = threadIdx.x;
    const int w    = tid >> 6, lane = tid & 63;
    const int m0   = blockIdx.y * 128;

    const __half* Wsel; const float* bsel; float* osel; float scale; int n0;
    if (MODE == 0) {
        const int sel = blockIdx.x >> 3;
        n0   = (blockIdx.x & 7) * 128;
        Wsel = sel == 0 ? Wa : (sel == 1 ? Wb : Wc);
        bsel = sel == 0 ? ba : (sel == 1 ? bb : bc);
        osel = sel == 0 ? oa : (sel == 1 ? ob : oc);
        scale = (sel == 0) ? 0.125f : 1.0f;   // q pre-scaled by hd^-0.5
    } else {
        n0 = blockIdx.x * 128; Wsel = Wa; bsel = ba; osel = oa; scale = 1.0f;
    }

    f32x4 acc[4][4];
    #pragma unroll
    for (int i = 0; i < 4; ++i)
        #pragma unroll
        for (int j = 0; j < 4; ++j) acc[i][j] = (f32x4){0.f, 0.f, 0.f, 0.f};

    const int wr = w >> 1, wc = w & 1;
    const int lrow = lane & 15, lkg = lane >> 4;
    // LDS fragment byte offsets (row*64B + kgroup*16B)
    const int a_off0 = (wr * 64 + lrow) * 64 + lkg * 16;
    const int b_off0 = (wc * 64 + lrow) * 64 + lkg * 16;

    // staging: wave w owns tile bytes [w*2048, w*2048+2048), 2 chunks of 1024 B
    const int chunkbase = w * 2048;
    const char* Ab = (const char*)A;
    const char* Wb8 = (const char*)Wsel;

    for (int k0 = 0; k0 < EE; k0 += 32) {
        #pragma unroll
        for (int i = 0; i < 2; ++i) {
            const int off  = chunkbase + i * 1024 + lane * 16;  // byte in tile
            const int row  = off >> 6;
            const int colb = off & 63;
            gl_lds16(Ab  + (size_t)(m0 + row) * 2048 + k0 * 2 + colb,
                     (char*)As + chunkbase + i * 1024);
            gl_lds16(Wb8 + (size_t)(n0 + row) * 2048 + k0 * 2 + colb,
                     (char*)Bs + chunkbase + i * 1024);
        }
        __syncthreads();   // drains vmcnt: LDS tiles ready

        half8 af[4], bf[4];
        #pragma unroll
        for (int m = 0; m < 4; ++m) af[m] = *(const half8*)((const char*)As + a_off0 + m * 1024);
        #pragma unroll
        for (int n = 0; n < 4; ++n) bf[n] = *(const half8*)((const char*)Bs + b_off0 + n * 1024);
        #pragma unroll
        for (int m = 0; m < 4; ++m)
            #pragma unroll
            for (int n = 0; n < 4; ++n)
                acc[m][n] = __builtin_amdgcn_mfma_f32_16x16x32_f16(af[m], bf[n], acc[m][n], 0, 0, 0);
        __syncthreads();   // frag reads done before next-tile overwrite
    }

    // epilogue: C/D layout col = lane&15, row = (lane>>4)*4 + reg
    const int col_l  = lane & 15;
    const int row_l4 = (lane >> 4) * 4;
    #pragma unroll
    for (int n = 0; n < 4; ++n) {
        const int gcol = n0 + wc * 64 + n * 16 + col_l;
        const float bias = bsel[gcol];
        #pragma unroll
        for (int m = 0; m < 4; ++m) {
            #pragma unroll
            for (int j = 0; j < 4; ++j) {
                const int grow = m0 + wr * 64 + m * 16 + row_l4 + j;
                const float cval = (acc[m][n][j] + bias) * scale;
                if (MODE == 0) {
                    const int t3 = grow >> 2, b = grow & 3;
                    const int h = gcol >> 6, d = gcol & 63;
                    osel[(((size_t)(b * HH + h)) * T3 + t3) * HD + d] = cval;
                } else if (MODE == 1) {
                    const int t3 = grow >> 2, b = grow & 3;
                    const int st = t3 >> 9, tm = t3 & 511;
                    const int nb = gcol >> 4, h = gcol & 15;
                    osel[(((size_t)(st * BHH + b * HH + h)) * TMQ + tm) * NBK + nb] = cval;
                } else {
                    osel[(size_t)grow * EE + gcol] = cval;
                }
            }
        }
    }
}

// ---------------------------------------------------------------------------
// Fused flash-style attention (fp32), one block = (stream s, head bh, 64 q-rows).
// Unchanged from round 1 except: output written as fp16 (feeds Wo MFMA GEMM).
// ---------------------------------------------------------------------------
__global__ __launch_bounds__(256) void attn_fused(
    const float* __restrict__ q, const float* __restrict__ k,
    const float* __restrict__ v, const float* __restrict__ vals,
    const float* __restrict__ self_mask, const float* __restrict__ ngram_mask,
    const int* __restrict__ ibm, const int* __restrict__ ibr,
    __half* __restrict__ attn_pre)
{
    __shared__ float Qs[64][68];       // [d][row] transposed
    __shared__ float KVs[64][68];      // K phase: [d][key] ; V phase: [key][d]
    __shared__ float Ps[64][68];       // [row][key]
    __shared__ float vals_s[64][NBK];  // per-row bucket logits

    const int bid = blockIdx.x;
    int s, bh, qt;
    if (bid < 512) { s = 0; bh = bid >> 3; qt = bid & 7; }
    else { const int rr = bid - 512; s = 1 + (rr >> 9); bh = (rr >> 3) & 63; qt = rr & 7; }
    const int b = bh >> 4, h = bh & 15;
    const int tid = threadIdx.x;
    const int tx = tid & 15, ty = tid >> 4;
    const int lr = tid >> 2, lq = tid & 3;   // loader row / quad

    // ---- stage Q tile (transposed) + vals rows ----
    {
        const float* qp = q + ((size_t)bh * T3 + s * TMQ + qt * 64 + lr) * HD;
        #pragma unroll
        for (int rep = 0; rep < 4; ++rep) {
            const int qd = lq + rep * 4;
            const float4 t4 = *(const float4*)(qp + qd * 4);
            Qs[qd*4+0][lr]=t4.x; Qs[qd*4+1][lr]=t4.y; Qs[qd*4+2][lr]=t4.z; Qs[qd*4+3][lr]=t4.w;
        }
        const float* vp = vals + (((size_t)s * BHH + bh) * TMQ + qt * 64) * NBK;
        #pragma unroll
        for (int rep = 0; rep < 2; ++rep) {
            const int idx4 = tid + rep * 256;
            const int rrow = idx4 >> 3, qq = idx4 & 7;
            *(float4*)&vals_s[rrow][qq*4] = *(const float4*)(vp + rrow*NBK + qq*4);
        }
    }

    float m_i[4], l_i[4], o[4][4];
    #pragma unroll
    for (int i = 0; i < 4; ++i) {
        m_i[i] = -1e30f; l_i[i] = 0.f;
        o[i][0]=0.f; o[i][1]=0.f; o[i][2]=0.f; o[i][3]=0.f;
    }

    const int nch = (s == 0) ? 8 : 16;
    for (int c = 0; c < nch; ++c) {
        const int jg0 = c * 64;
        // ---- K chunk -> KVs[d][key] (transposed) ----
        {
            const int jg = jg0 + lr;
            const int t3k = (jg < TMQ) ? jg : (s * TMQ + jg - TMQ);
            const float* kp = k + ((size_t)bh * T3 + t3k) * HD;
            #pragma unroll
            for (int rep = 0; rep < 4; ++rep) {
                const int qd = lq + rep * 4;
                const float4 t4 = *(const float4*)(kp + qd * 4);
                KVs[qd*4+0][lr]=t4.x; KVs[qd*4+1][lr]=t4.y; KVs[qd*4+2][lr]=t4.z; KVs[qd*4+3][lr]=t4.w;
            }
        }
        __syncthreads();

        // ---- scores: 4x4 micro GEMM over d ----
        float sc[4][4] = {};
        #pragma unroll 8
        for (int d = 0; d < 64; ++d) {
            const float4 qa = *(const float4*)&Qs[d][ty*4];
            const float4 kb = *(const float4*)&KVs[d][tx*4];
            const float qr[4] = {qa.x,qa.y,qa.z,qa.w};
            const float kr[4] = {kb.x,kb.y,kb.z,kb.w};
            #pragma unroll
            for (int i = 0; i < 4; ++i) {
                #pragma unroll
                for (int j = 0; j < 4; ++j) sc[i][j] += qr[i] * kr[j];
            }
        }

        // ---- epilogue: bucket-gathered rel logits + additive mask ----
        #pragma unroll
        for (int i = 0; i < 4; ++i) {
            const int tl = ty*4 + i;
            const int t  = qt*64 + tl;
            #pragma unroll
            for (int j = 0; j < 4; ++j) {
                const int jj = jg0 + tx*4 + j;
                int idx; float msk;
                if (s == 0) {
                    idx = ibm[((size_t)b * TMQ + t) * TMQ + jj];
                    msk = self_mask[(size_t)t * TMQ + jj];
                } else {
                    idx = ibr[((size_t)b * TMQ + t) * (2*TMQ) + jj];
                    msk = ngram_mask[((size_t)(s-1) * TMQ + t) * (2*TMQ) + jj];
                }
                sc[i][j] += vals_s[tl][idx] + msk;
            }
        }

        // ---- online softmax (reduce over 16-lane tx group) + stage P ----
        #pragma unroll
        for (int i = 0; i < 4; ++i) {
            const int tl = ty*4 + i;
            float rm = fmaxf(fmaxf(sc[i][0], sc[i][1]), fmaxf(sc[i][2], sc[i][3]));
            rm = fmaxf(rm, __shfl_xor(rm, 1));
            rm = fmaxf(rm, __shfl_xor(rm, 2));
            rm = fmaxf(rm, __shfl_xor(rm, 4));
            rm = fmaxf(rm, __shfl_xor(rm, 8));
            const float mn   = fmaxf(m_i[i], rm);
            const float corr = __expf(m_i[i] - mn);
            float p[4];
            #pragma unroll
            for (int j = 0; j < 4; ++j) p[j] = __expf(sc[i][j] - mn);
            float rs = p[0] + p[1] + p[2] + p[3];
            rs += __shfl_xor(rs, 1);
            rs += __shfl_xor(rs, 2);
            rs += __shfl_xor(rs, 4);
            rs += __shfl_xor(rs, 8);
            l_i[i] = l_i[i] * corr + rs;
            m_i[i] = mn;
            #pragma unroll
            for (int j = 0; j < 4; ++j) o[i][j] *= corr;
            float4 p4; p4.x=p[0]; p4.y=p[1]; p4.z=p[2]; p4.w=p[3];
            *(float4*)&Ps[tl][tx*4] = p4;
        }
        __syncthreads();   // P visible; all score-phase KVs reads done

        // ---- V chunk -> KVs[key][d] ----
        {
            const int jg = jg0 + lr;
            const int t3k = (jg < TMQ) ? jg : (s * TMQ + jg - TMQ);
            const float* vp2 = v + ((size_t)bh * T3 + t3k) * HD;
            #pragma unroll
            for (int rep = 0; rep < 4; ++rep) {
                const int qd = lq + rep * 4;
                *(float4*)&KVs[lr][qd*4] = *(const float4*)(vp2 + qd * 4);
            }
        }
        __syncthreads();

        // ---- O += P * V (4x4 micro over 64 keys) ----
        #pragma unroll 4
        for (int j4 = 0; j4 < 16; ++j4) {
            const float4 p0 = *(const float4*)&Ps[ty*4+0][j4*4];
            const float4 p1 = *(const float4*)&Ps[ty*4+1][j4*4];
            const float4 p2 = *(const float4*)&Ps[ty*4+2][j4*4];
            const float4 p3 = *(const float4*)&Ps[ty*4+3][j4*4];
            const float pr[4][4] = {{p0.x,p0.y,p0.z,p0.w},
                                    {p1.x,p1.y,p1.z,p1.w},
                                    {p2.x,p2.y,p2.z,p2.w},
                                    {p3.x,p3.y,p3.z,p3.w}};
            #pragma unroll
            for (int u = 0; u < 4; ++u) {
                const float4 vv = *(const float4*)&KVs[j4*4+u][tx*4];
                #pragma unroll
                for (int i = 0; i < 4; ++i) {
                    o[i][0] += pr[i][u] * vv.x;
                    o[i][1] += pr[i][u] * vv.y;
                    o[i][2] += pr[i][u] * vv.z;
                    o[i][3] += pr[i][u] * vv.w;
                }
            }
        }
        __syncthreads();   // PV done before next chunk overwrites KVs/Ps
    }

    // ---- normalize + write fp16 to attn_pre (T3, B, E) ----
    #pragma unroll
    for (int i = 0; i < 4; ++i) {
        const float inv = 1.0f / l_i[i];
        const int t = qt*64 + ty*4 + i;
        __half2* ap = (__half2*)(attn_pre + (((size_t)(s * TMQ + t)) * BB + b) * EE + h * HD + tx * 4);
        ap[0] = __floats2half2_rn(o[i][0]*inv, o[i][1]*inv);
        ap[1] = __floats2half2_rn(o[i][2]*inv, o[i][3]*inv);
    }
}

// ---------------------------------------------------------------------------
// Launcher. Workspace (float units):
//   qw/kw/vw: 3 x 6,291,456 | valsw: 3,145,728 | hs_h (fp16, aliased by apre_h):
//   3,145,728 | Wq/Wk/Wv/Wo_h: 4 x 524,288 | Wr_h: 262,144  => ~27.4M fl = 110 MB
// ---------------------------------------------------------------------------
extern "C" void kernel_launch(void* const* d_in, const int* in_sizes, int n_in,
                              void* d_out, int out_size, void* d_ws, size_t ws_size,
                              hipStream_t stream)
{
    const float* hs    = (const float*)d_in[0];
    const float* smask = (const float*)d_in[1];
    const float* nmask = (const float*)d_in[2];
    const int*   ibm   = (const int*)d_in[3];
    const int*   ibr   = (const int*)d_in[4];
    const float* Wq = (const float*)d_in[5];
    const float* bq = (const float*)d_in[6];
    const float* Wk = (const float*)d_in[7];
    const float* bk = (const float*)d_in[8];
    const float* Wv = (const float*)d_in[9];
    const float* bv = (const float*)d_in[10];
    const float* Wo = (const float*)d_in[11];
    const float* bo = (const float*)d_in[12];
    const float* Wr = (const float*)d_in[13];
    const float* br = (const float*)d_in[14];
    float* out = (float*)d_out;
    float* ws  = (float*)d_ws;

    float* qw    = ws;                                   // 6,291,456 f
    float* kw    = qw + (size_t)BHH * T3 * HD;           // 6,291,456 f
    float* vw    = kw + (size_t)BHH * T3 * HD;           // 6,291,456 f
    float* valsw = vw + (size_t)BHH * T3 * HD;           // 3,145,728 f
    __half* hs_h = (__half*)(valsw + (size_t)3 * BHH * TMQ * NBK);  // 6,291,456 h
    __half* apre_h = hs_h;                               // alias: hs_h dead before attn writes
    __half* Wq_h = hs_h + (size_t)T3 * BB * EE;          // 1,048,576 h each
    __half* Wk_h = Wq_h + (size_t)EE * EE;
    __half* Wv_h = Wk_h + (size_t)EE * EE;
    __half* Wo_h = Wv_h + (size_t)EE * EE;
    __half* Wr_h = Wo_h + (size_t)EE * EE;               // 524,288 h

    dim3 blk(256);
    // fp32 -> fp16 conversions
    cvt16<<<dim3(6144), blk, 0, stream>>>(hs, hs_h, T3 * BB * EE);
    cvt16<<<dim3(1024), blk, 0, stream>>>(Wq, Wq_h, EE * EE);
    cvt16<<<dim3(1024), blk, 0, stream>>>(Wk, Wk_h, EE * EE);
    cvt16<<<dim3(1024), blk, 0, stream>>>(Wv, Wv_h, EE * EE);
    cvt16<<<dim3(1024), blk, 0, stream>>>(Wo, Wo_h, EE * EE);
    cvt16<<<dim3(512),  blk, 0, stream>>>(Wr, Wr_h, NBK * HH * EE);

    // fused QKV projection (MFMA): 24 x 48 blocks
    gemm16<0><<<dim3(24, 48), blk, 0, stream>>>(hs_h, Wq_h, Wk_h, Wv_h,
                                                bq, bk, bv, qw, kw, vw);
    // relative-bucket projection: N=512
    gemm16<1><<<dim3(4, 48), blk, 0, stream>>>(hs_h, Wr_h, nullptr, nullptr,
                                               br, nullptr, nullptr,
                                               valsw, nullptr, nullptr);
    // fused attention (reads qw/kw/vw/valsw; writes fp16 apre_h — hs_h now dead)
    attn_fused<<<dim3(1536), blk, 0, stream>>>(qw, kw, vw, valsw, smask, nmask,
                                               ibm, ibr, apre_h);
    // output projection -> d_out
    gemm16<2><<<dim3(8, 48), blk, 0, stream>>>(apre_h, Wo_h, nullptr, nullptr,
                                               bo, nullptr, nullptr,
                                               out, nullptr, nullptr);
}

// Round 3
// 273.258 us; speedup vs baseline: 4.4839x; 1.8705x over previous
//
#include <hip/hip_runtime.h>
#include <hip/hip_fp16.h>
#include <cstdint>

// Problem constants
#define T3   1536   // (NGRAM+1)*TM
#define TMQ  512    // TM
#define BB   4      // batch
#define EE   1024   // embed
#define HH   16     // heads
#define HD   64     // head dim
#define NBK  32     // buckets
#define BHH  64     // B*H

typedef _Float16 half8 __attribute__((ext_vector_type(8)));
typedef float    f32x4 __attribute__((ext_vector_type(4)));

// XOR swizzle for [64][64] fp16 tiles (128B rows): spreads the 128B row
// stride across 8 16B slots -> ds_read_b128 fragment reads conflict-free (T2/G4).
#define SWZ(r, o) ((o) ^ (((r) & 7) << 4))

__device__ inline void gl_lds16(const void* g, void* l) {
    __builtin_amdgcn_global_load_lds(
        (const __attribute__((address_space(1))) uint32_t*)g,
        (__attribute__((address_space(3))) uint32_t*)l, 16, 0, 0);
}

// ---------------------------------------------------------------------------
// fp32 -> fp16 conversion (vectorized, n % 4 == 0)
// ---------------------------------------------------------------------------
__global__ __launch_bounds__(256) void cvt16(
    const float* __restrict__ in, __half* __restrict__ out, int n)
{
    const int i = (blockIdx.x * blockDim.x + threadIdx.x) * 4;
    if (i < n) {
        const float4 v = *(const float4*)(in + i);
        __half2* o = (__half2*)(out + i);
        o[0] = __floats2half2_rn(v.x, v.y);
        o[1] = __floats2half2_rn(v.z, v.w);
    }
}

// ---------------------------------------------------------------------------
// fp16 MFMA GEMM (NT): C = (A @ W^T + bias) * scale, K = 1024.
// BM=BN=128, BK=32, 256 thr (4 waves 2x2), 16x16x32 MFMA, global_load_lds.
// MODE 0: fused QKV. sel 0/1 (q,k) -> fp16 (BH,T3,hd); sel 2 (v) -> fp16
//         TRANSPOSED (BH,hd,T3)  [feeds attention PV B-operand directly]
// MODE 1: Wr -> fp32 vals (stream, BH, TM, NB); N=512
// MODE 2: Wo -> fp32 plain row-major (M, 1024)
// ---------------------------------------------------------------------------
template<int MODE>
__global__ __launch_bounds__(256) void gemm16(
    const __half* __restrict__ A,
    const __half* __restrict__ Wa, const __half* __restrict__ Wb, const __half* __restrict__ Wc,
    const float* __restrict__ ba, const float* __restrict__ bb, const float* __restrict__ bc,
    void* __restrict__ oa, void* __restrict__ ob, void* __restrict__ oc)
{
    __shared__ __half As[128 * 32];   // [row][k] row-major, 64 B per row
    __shared__ __half Bs[128 * 32];

    const int tid  = threadIdx.x;
    const int w    = tid >> 6, lane = tid & 63;
    const int m0   = blockIdx.y * 128;

    const __half* Wsel; const float* bsel; void* osel; float scale; int n0; int sel = 0;
    if (MODE == 0) {
        sel  = blockIdx.x >> 3;
        n0   = (blockIdx.x & 7) * 128;
        Wsel = sel == 0 ? Wa : (sel == 1 ? Wb : Wc);
        bsel = sel == 0 ? ba : (sel == 1 ? bb : bc);
        osel = sel == 0 ? oa : (sel == 1 ? ob : oc);
        scale = (sel == 0) ? 0.125f : 1.0f;   // q pre-scaled by hd^-0.5
    } else {
        n0 = blockIdx.x * 128; Wsel = Wa; bsel = ba; osel = oa; scale = 1.0f;
    }

    f32x4 acc[4][4];
    #pragma unroll
    for (int i = 0; i < 4; ++i)
        #pragma unroll
        for (int j = 0; j < 4; ++j) acc[i][j] = (f32x4){0.f, 0.f, 0.f, 0.f};

    const int wr = w >> 1, wc = w & 1;
    const int lrow = lane & 15, lkg = lane >> 4;
    const int a_off0 = (wr * 64 + lrow) * 64 + lkg * 16;
    const int b_off0 = (wc * 64 + lrow) * 64 + lkg * 16;

    const int chunkbase = w * 2048;
    const char* Ab  = (const char*)A;
    const char* Wb8 = (const char*)Wsel;

    for (int k0 = 0; k0 < EE; k0 += 32) {
        #pragma unroll
        for (int i = 0; i < 2; ++i) {
            const int off  = chunkbase + i * 1024 + lane * 16;
            const int row  = off >> 6;
            const int colb = off & 63;
            gl_lds16(Ab  + (size_t)(m0 + row) * 2048 + k0 * 2 + colb,
                     (char*)As + chunkbase + i * 1024);
            gl_lds16(Wb8 + (size_t)(n0 + row) * 2048 + k0 * 2 + colb,
                     (char*)Bs + chunkbase + i * 1024);
        }
        __syncthreads();

        half8 af[4], bf[4];
        #pragma unroll
        for (int m = 0; m < 4; ++m) af[m] = *(const half8*)((const char*)As + a_off0 + m * 1024);
        #pragma unroll
        for (int n = 0; n < 4; ++n) bf[n] = *(const half8*)((const char*)Bs + b_off0 + n * 1024);
        #pragma unroll
        for (int m = 0; m < 4; ++m)
            #pragma unroll
            for (int n = 0; n < 4; ++n)
                acc[m][n] = __builtin_amdgcn_mfma_f32_16x16x32_f16(af[m], bf[n], acc[m][n], 0, 0, 0);
        __syncthreads();
    }

    // epilogue: C/D layout col = lane&15, row = (lane>>4)*4 + reg
    const int col_l  = lane & 15;
    const int row_l4 = (lane >> 4) * 4;
    #pragma unroll
    for (int n = 0; n < 4; ++n) {
        const int gcol = n0 + wc * 64 + n * 16 + col_l;
        const float bias = bsel[gcol];
        #pragma unroll
        for (int m = 0; m < 4; ++m) {
            #pragma unroll
            for (int j = 0; j < 4; ++j) {
                const int grow = m0 + wr * 64 + m * 16 + row_l4 + j;
                const float cval = (acc[m][n][j] + bias) * scale;
                if (MODE == 0) {
                    const int t3 = grow >> 2, bb2 = grow & 3;
                    const int hh2 = gcol >> 6, d = gcol & 63;
                    __half* oh = (__half*)osel;
                    const __half hv = __float2half(cval);
                    if (sel == 2)  // V transposed: (BH, hd, T3)
                        oh[((size_t)((bb2 * HH + hh2) * HD + d)) * T3 + t3] = hv;
                    else           // Q, K: (BH, T3, hd)
                        oh[(((size_t)(bb2 * HH + hh2)) * T3 + t3) * HD + d] = hv;
                } else if (MODE == 1) {
                    const int t3 = grow >> 2, bb2 = grow & 3;
                    const int st = t3 >> 9, tm = t3 & 511;
                    const int nb = gcol >> 4, hh2 = gcol & 15;
                    ((float*)osel)[(((size_t)(st * BHH + bb2 * HH + hh2)) * TMQ + tm) * NBK + nb] = cval;
                } else {
                    ((float*)osel)[(size_t)grow * EE + gcol] = cval;
                }
            }
        }
    }
}

// ---------------------------------------------------------------------------
// MFMA fused attention. Block = (stream s, head bh, 64 q-rows), 4 waves,
// wave = 16 q-rows. Per 64-key chunk: QK^T (8 MFMA), bucket-gather + mask
// epilogue in C-layout, online softmax (stats align with O rows -> no
// cross-lane fixups), P -> fp16 LDS (per-wave slice), PV (8 MFMA).
// All fp16 LDS tiles XOR-swizzled. XCD-chunked bid swizzle for L2 locality.
// ---------------------------------------------------------------------------
__global__ __launch_bounds__(256) void attn_mfma(
    const __half* __restrict__ q, const __half* __restrict__ k,
    const __half* __restrict__ vt, const float* __restrict__ vals,
    const float* __restrict__ self_mask, const float* __restrict__ ngram_mask,
    const int* __restrict__ ibm, const int* __restrict__ ibr,
    __half* __restrict__ attn_pre)
{
    __shared__ __half Qs [64 * 64];    // [q][d]    swizzled
    __shared__ __half Ks [64 * 64];    // [key][d]  swizzled
    __shared__ __half Vts[64 * 64];    // [d][key]  swizzled
    __shared__ __half Pa [64 * 64];    // [q][key]  swizzled (per-wave 16-row slice)
    __shared__ float  vals_s[64 * NBK];

    // XCD-chunked swizzle: 1536 blocks, 8 XCDs -> 192 consecutive wids per XCD
    const int bid = blockIdx.x;
    const int wid = (bid & 7) * 192 + (bid >> 3);
    int s, bh, qt;
    if (wid < 512) { s = 0; bh = wid >> 3; qt = wid & 7; }
    else { const int rr = wid - 512; s = 1 + (rr >> 9); bh = (rr >> 3) & 63; qt = rr & 7; }
    const int b = bh >> 4, h = bh & 15;
    const int tid = threadIdx.x;
    const int w = tid >> 6, lane = tid & 63;
    const int lc = lane & 15, lg = lane >> 4;

    // ---- stage Q (swizzled) + vals (linear); both tiles contiguous 8 KB ----
    {
        const char* qg = (const char*)(q + ((size_t)bh * T3 + s * TMQ + qt * 64) * HD);
        const char* vg = (const char*)(vals + (((size_t)s * BHH + bh) * TMQ + qt * 64) * NBK);
        #pragma unroll
        for (int p = 0; p < 2; ++p) {
            const int u = tid + p * 256;
            const int row = u >> 3, sub = (u & 7) * 16;
            *(uint4*)((char*)Qs + row * 128 + SWZ(row, sub)) = *(const uint4*)(qg + (size_t)u * 16);
            *(uint4*)((char*)vals_s + (size_t)u * 16)         = *(const uint4*)(vg + (size_t)u * 16);
        }
    }
    __syncthreads();

    // hoisted Q A-fragments (row = local q = w*16 + lc)
    half8 aq[2];
    {
        const int qr = w * 16 + lc;
        const char* qb = (const char*)Qs + qr * 128;
        aq[0] = *(const half8*)(qb + SWZ(qr, lg * 16));
        aq[1] = *(const half8*)(qb + SWZ(qr, 64 + lg * 16));
    }

    f32x4 o[4];
    #pragma unroll
    for (int nd = 0; nd < 4; ++nd) o[nd] = (f32x4){0.f, 0.f, 0.f, 0.f};
    float m_i[4], l_i[4];
    #pragma unroll
    for (int j = 0; j < 4; ++j) { m_i[j] = -1e30f; l_i[j] = 0.f; }

    const int nch = (s == 0) ? 8 : 16;
    for (int c = 0; c < nch; ++c) {
        const int jg0 = c * 64;
        const int t3b = (jg0 < TMQ) ? jg0 : (s * TMQ + (jg0 - TMQ));

        // ---- stage K chunk (contiguous 8 KB) + Vt chunk (64 rows x 128B) ----
        {
            const char* kg = (const char*)(k + ((size_t)bh * T3 + t3b) * HD);
            const char* vg = (const char*)(vt + (size_t)bh * HD * T3 + t3b);
            #pragma unroll
            for (int p = 0; p < 2; ++p) {
                const int u = tid + p * 256;
                const int row = u >> 3, sub = (u & 7) * 16;
                *(uint4*)((char*)Ks  + row * 128 + SWZ(row, sub)) =
                    *(const uint4*)(kg + (size_t)u * 16);
                *(uint4*)((char*)Vts + row * 128 + SWZ(row, sub)) =
                    *(const uint4*)(vg + (size_t)row * (T3 * 2) + sub);
            }
        }
        __syncthreads();

        // ---- QK^T: D[q_local][key] ----
        f32x4 sc[4];
        #pragma unroll
        for (int n = 0; n < 4; ++n) sc[n] = (f32x4){0.f, 0.f, 0.f, 0.f};
        #pragma unroll
        for (int ks = 0; ks < 2; ++ks) {
            #pragma unroll
            for (int n = 0; n < 4; ++n) {
                const int kr = n * 16 + lc;
                const half8 bk = *(const half8*)((const char*)Ks + kr * 128 + SWZ(kr, ks * 64 + lg * 16));
                sc[n] = __builtin_amdgcn_mfma_f32_16x16x32_f16(aq[ks], bk, sc[n], 0, 0, 0);
            }
        }

        // ---- gather + mask + online softmax + P write (C-layout) ----
        // element: row q_local = w*16 + lg*4 + j, col key = n*16 + lc
        #pragma unroll
        for (int j = 0; j < 4; ++j) {
            const int ql = w * 16 + lg * 4 + j;     // local q row
            const int t  = qt * 64 + ql;            // global t
            const int* ip; const float* mp;
            if (s == 0) {
                ip = ibm + ((size_t)b * TMQ + t) * TMQ + jg0 + lc;
                mp = self_mask + (size_t)t * TMQ + jg0 + lc;
            } else {
                ip = ibr + ((size_t)b * TMQ + t) * (2 * TMQ) + jg0 + lc;
                mp = ngram_mask + ((size_t)(s - 1) * TMQ + t) * (2 * TMQ) + jg0 + lc;
            }
            const float* vr = vals_s + ql * NBK;
            float sv[4];
            #pragma unroll
            for (int n = 0; n < 4; ++n)
                sv[n] = sc[n][j] + vr[ip[n * 16]] + mp[n * 16];

            float rm = fmaxf(fmaxf(sv[0], sv[1]), fmaxf(sv[2], sv[3]));
            rm = fmaxf(rm, __shfl_xor(rm, 1));
            rm = fmaxf(rm, __shfl_xor(rm, 2));
            rm = fmaxf(rm, __shfl_xor(rm, 4));
            rm = fmaxf(rm, __shfl_xor(rm, 8));
            const float mn   = fmaxf(m_i[j], rm);
            const float corr = __expf(m_i[j] - mn);
            m_i[j] = mn;
            float p0 = __expf(sv[0] - mn), p1 = __expf(sv[1] - mn);
            float p2 = __expf(sv[2] - mn), p3 = __expf(sv[3] - mn);
            float rs = p0 + p1 + p2 + p3;
            rs += __shfl_xor(rs, 1);
            rs += __shfl_xor(rs, 2);
            rs += __shfl_xor(rs, 4);
            rs += __shfl_xor(rs, 8);
            l_i[j] = l_i[j] * corr + rs;
            #pragma unroll
            for (int nd = 0; nd < 4; ++nd) o[nd][j] *= corr;

            char* pb = (char*)Pa + ql * 128;
            *(__half*)(pb + SWZ(ql, (0 * 16 + lc) * 2)) = __float2half(p0);
            *(__half*)(pb + SWZ(ql, (1 * 16 + lc) * 2)) = __float2half(p1);
            *(__half*)(pb + SWZ(ql, (2 * 16 + lc) * 2)) = __float2half(p2);
            *(__half*)(pb + SWZ(ql, (3 * 16 + lc) * 2)) = __float2half(p3);
        }
        __threadfence_block();   // P-writes visible within wave (Pa slice is per-wave)

        // ---- PV: O[q_local][d] += P[q][key] * Vt[d][key] ----
        #pragma unroll
        for (int ks = 0; ks < 2; ++ks) {
            const int ar = w * 16 + lc;
            const half8 ap = *(const half8*)((const char*)Pa + ar * 128 + SWZ(ar, ks * 64 + lg * 16));
            #pragma unroll
            for (int nd = 0; nd < 4; ++nd) {
                const int vr2 = nd * 16 + lc;
                const half8 bv = *(const half8*)((const char*)Vts + vr2 * 128 + SWZ(vr2, ks * 64 + lg * 16));
                o[nd] = __builtin_amdgcn_mfma_f32_16x16x32_f16(ap, bv, o[nd], 0, 0, 0);
            }
        }
        __syncthreads();   // all waves done with Ks/Vts before next chunk staging
    }

    // ---- normalize + write fp16 attn_pre (T3, B, E) ----
    #pragma unroll
    for (int j = 0; j < 4; ++j) {
        const float inv = 1.0f / l_i[j];
        const int t = qt * 64 + w * 16 + lg * 4 + j;
        __half* op = attn_pre + (((size_t)(s * TMQ + t)) * BB + b) * EE + h * HD + lc;
        #pragma unroll
        for (int nd = 0; nd < 4; ++nd)
            op[nd * 16] = __float2half(o[nd][j] * inv);
    }
}

// ---------------------------------------------------------------------------
// Launcher. Workspace: qh/kh/vth 12 MB each (fp16) | valsw 12 MB (fp32) |
// hs_h 12 MB (fp16, aliased by apre_h) | weights fp16 9 MB  => ~69 MB
// ---------------------------------------------------------------------------
extern "C" void kernel_launch(void* const* d_in, const int* in_sizes, int n_in,
                              void* d_out, int out_size, void* d_ws, size_t ws_size,
                              hipStream_t stream)
{
    const float* hs    = (const float*)d_in[0];
    const float* smask = (const float*)d_in[1];
    const float* nmask = (const float*)d_in[2];
    const int*   ibm   = (const int*)d_in[3];
    const int*   ibr   = (const int*)d_in[4];
    const float* Wq = (const float*)d_in[5];
    const float* bq = (const float*)d_in[6];
    const float* Wk = (const float*)d_in[7];
    const float* bk = (const float*)d_in[8];
    const float* Wv = (const float*)d_in[9];
    const float* bv = (const float*)d_in[10];
    const float* Wo = (const float*)d_in[11];
    const float* bo = (const float*)d_in[12];
    const float* Wr = (const float*)d_in[13];
    const float* br = (const float*)d_in[14];
    float* out = (float*)d_out;

    const size_t NQKV = (size_t)BHH * T3 * HD;   // 6,291,456
    __half* qh    = (__half*)d_ws;
    __half* kh    = qh + NQKV;
    __half* vth   = kh + NQKV;
    float*  valsw = (float*)(vth + NQKV);
    __half* hs_h  = (__half*)(valsw + (size_t)3 * BHH * TMQ * NBK);
    __half* apre_h = hs_h;                        // alias: hs_h dead before attn writes
    __half* Wq_h = hs_h + (size_t)T3 * BB * EE;
    __half* Wk_h = Wq_h + (size_t)EE * EE;
    __half* Wv_h = Wk_h + (size_t)EE * EE;
    __half* Wo_h = Wv_h + (size_t)EE * EE;
    __half* Wr_h = Wo_h + (size_t)EE * EE;

    dim3 blk(256);
    cvt16<<<dim3(6144), blk, 0, stream>>>(hs, hs_h, T3 * BB * EE);
    cvt16<<<dim3(1024), blk, 0, stream>>>(Wq, Wq_h, EE * EE);
    cvt16<<<dim3(1024), blk, 0, stream>>>(Wk, Wk_h, EE * EE);
    cvt16<<<dim3(1024), blk, 0, stream>>>(Wv, Wv_h, EE * EE);
    cvt16<<<dim3(1024), blk, 0, stream>>>(Wo, Wo_h, EE * EE);
    cvt16<<<dim3(512),  blk, 0, stream>>>(Wr, Wr_h, NBK * HH * EE);

    // fused QKV projection (q,k -> (BH,T3,hd) fp16; v -> (BH,hd,T3) fp16)
    gemm16<0><<<dim3(24, 48), blk, 0, stream>>>(hs_h, Wq_h, Wk_h, Wv_h,
                                                bq, bk, bv, qh, kh, vth);
    // relative-bucket projection (fp32 vals)
    gemm16<1><<<dim3(4, 48), blk, 0, stream>>>(hs_h, Wr_h, nullptr, nullptr,
                                               br, nullptr, nullptr,
                                               valsw, nullptr, nullptr);
    // MFMA fused attention -> fp16 apre (hs_h now dead)
    attn_mfma<<<dim3(1536), blk, 0, stream>>>(qh, kh, vth, valsw, smask, nmask,
                                              ibm, ibr, apre_h);
    // output projection -> d_out (fp32)
    gemm16<2><<<dim3(8, 48), blk, 0, stream>>>(apre_h, Wo_h, nullptr, nullptr,
                                               bo, nullptr, nullptr,
                                               out, nullptr, nullptr);
}

// Round 4
// 250.039 us; speedup vs baseline: 4.9003x; 1.0929x over previous
//
#include <hip/hip_runtime.h>
#include <hip/hip_fp16.h>
#include <cstdint>

// Problem constants
#define T3   1536   // (NGRAM+1)*TM
#define TMQ  512    // TM
#define BB   4      // batch
#define EE   1024   // embed
#define HH   16     // heads
#define HD   64     // head dim
#define NBK  32     // buckets
#define BHH  64     // B*H

typedef _Float16 half8 __attribute__((ext_vector_type(8)));
typedef float    f32x4 __attribute__((ext_vector_type(4)));

// XOR swizzle for [64][64] fp16 tiles (128B rows): spreads the 128B row
// stride across 8 16B slots -> ds_read_b128 fragment reads conflict-free (T2/G4).
#define SWZ(r, o) ((o) ^ (((r) & 7) << 4))

__device__ inline void gl_lds16(const void* g, void* l) {
    __builtin_amdgcn_global_load_lds(
        (const __attribute__((address_space(1))) uint32_t*)g,
        (__attribute__((address_space(3))) uint32_t*)l, 16, 0, 0);
}

// ---------------------------------------------------------------------------
// Fused fp32 -> fp16 conversion for all six tensors in ONE launch.
// Destination buffers are laid out contiguously: hs_h | Wq | Wk | Wv | Wo | Wr.
// vec4 segment sizes: hs 1,572,864 | weights 4 x 262,144 | Wr 131,072
// total = 2,752,512 vec4 -> 10752 blocks x 256.
// ---------------------------------------------------------------------------
__global__ __launch_bounds__(256) void cvt_all(
    const float* __restrict__ hs, const float* __restrict__ Wq,
    const float* __restrict__ Wk, const float* __restrict__ Wv,
    const float* __restrict__ Wo, const float* __restrict__ Wr,
    __half* __restrict__ dst)
{
    const long i = (long)blockIdx.x * 256 + threadIdx.x;   // vec4 index
    const float* src; long off;
    if (i < 1572864L) { src = hs; off = i; }
    else {
        const long j = i - 1572864L;
        const int  w = (int)(j >> 18);
        const long r = j & 262143L;
        src = (w == 0) ? Wq : (w == 1) ? Wk : (w == 2) ? Wv : (w == 3) ? Wo : Wr;
        off = r;
    }
    const float4 v = ((const float4*)src)[off];
    const __half2 h0 = __floats2half2_rn(v.x, v.y);
    const __half2 h1 = __floats2half2_rn(v.z, v.w);
    uint2 u;
    u.x = *(const unsigned int*)&h0;
    u.y = *(const unsigned int*)&h1;
    ((uint2*)dst)[i] = u;
}

// ---------------------------------------------------------------------------
// fp16 MFMA GEMM (NT): C = (A @ W^T + bias) * scale, K = 1024.
// BM=BN=128, BK=32, 256 thr (4 waves 2x2), 16x16x32 MFMA, global_load_lds.
// MODE 0: fused QKV+Wr, grid.x = 28.
//   sel 0/1 (q,k) -> fp16 (BH,T3,hd); sel 2 (v) -> fp16 TRANSPOSED (BH,hd,T3);
//   sel 3 (Wr, bx 24..27) -> fp32 vals (stream, BH, TM, NB)
// MODE 2: Wo -> fp32 plain row-major (M, 1024)
// ---------------------------------------------------------------------------
template<int MODE>
__global__ __launch_bounds__(256) void gemm16(
    const __half* __restrict__ A,
    const __half* __restrict__ Wa, const __half* __restrict__ Wb,
    const __half* __restrict__ Wc, const __half* __restrict__ Wd,
    const float* __restrict__ ba, const float* __restrict__ bb,
    const float* __restrict__ bc, const float* __restrict__ bd,
    void* __restrict__ oa, void* __restrict__ ob,
    void* __restrict__ oc, void* __restrict__ od)
{
    __shared__ __half As[128 * 32];   // [row][k] row-major, 64 B per row
    __shared__ __half Bs[128 * 32];

    const int tid  = threadIdx.x;
    const int w    = tid >> 6, lane = tid & 63;
    const int m0   = blockIdx.y * 128;

    const __half* Wsel; const float* bsel; void* osel; float scale; int n0; int sel = 0;
    if (MODE == 0) {
        const int bx = blockIdx.x;
        sel  = (bx < 24) ? (bx >> 3) : 3;
        n0   = (bx < 24) ? (bx & 7) * 128 : (bx - 24) * 128;
        Wsel = sel == 0 ? Wa : (sel == 1 ? Wb : (sel == 2 ? Wc : Wd));
        bsel = sel == 0 ? ba : (sel == 1 ? bb : (sel == 2 ? bc : bd));
        osel = sel == 0 ? oa : (sel == 1 ? ob : (sel == 2 ? oc : od));
        scale = (sel == 0) ? 0.125f : 1.0f;   // q pre-scaled by hd^-0.5
    } else {
        n0 = blockIdx.x * 128; Wsel = Wa; bsel = ba; osel = oa; scale = 1.0f;
    }

    f32x4 acc[4][4];
    #pragma unroll
    for (int i = 0; i < 4; ++i)
        #pragma unroll
        for (int j = 0; j < 4; ++j) acc[i][j] = (f32x4){0.f, 0.f, 0.f, 0.f};

    const int wr = w >> 1, wc = w & 1;
    const int lrow = lane & 15, lkg = lane >> 4;
    const int a_off0 = (wr * 64 + lrow) * 64 + lkg * 16;
    const int b_off0 = (wc * 64 + lrow) * 64 + lkg * 16;

    const int chunkbase = w * 2048;
    const char* Ab  = (const char*)A;
    const char* Wb8 = (const char*)Wsel;

    for (int k0 = 0; k0 < EE; k0 += 32) {
        #pragma unroll
        for (int i = 0; i < 2; ++i) {
            const int off  = chunkbase + i * 1024 + lane * 16;
            const int row  = off >> 6;
            const int colb = off & 63;
            gl_lds16(Ab  + (size_t)(m0 + row) * 2048 + k0 * 2 + colb,
                     (char*)As + chunkbase + i * 1024);
            gl_lds16(Wb8 + (size_t)(n0 + row) * 2048 + k0 * 2 + colb,
                     (char*)Bs + chunkbase + i * 1024);
        }
        __syncthreads();

        half8 af[4], bf[4];
        #pragma unroll
        for (int m = 0; m < 4; ++m) af[m] = *(const half8*)((const char*)As + a_off0 + m * 1024);
        #pragma unroll
        for (int n = 0; n < 4; ++n) bf[n] = *(const half8*)((const char*)Bs + b_off0 + n * 1024);
        #pragma unroll
        for (int m = 0; m < 4; ++m)
            #pragma unroll
            for (int n = 0; n < 4; ++n)
                acc[m][n] = __builtin_amdgcn_mfma_f32_16x16x32_f16(af[m], bf[n], acc[m][n], 0, 0, 0);
        __syncthreads();
    }

    // epilogue: C/D layout col = lane&15, row = (lane>>4)*4 + reg
    const int col_l  = lane & 15;
    const int row_l4 = (lane >> 4) * 4;
    #pragma unroll
    for (int n = 0; n < 4; ++n) {
        const int gcol = n0 + wc * 64 + n * 16 + col_l;
        const float bias = bsel[gcol];
        #pragma unroll
        for (int m = 0; m < 4; ++m) {
            #pragma unroll
            for (int j = 0; j < 4; ++j) {
                const int grow = m0 + wr * 64 + m * 16 + row_l4 + j;
                const float cval = (acc[m][n][j] + bias) * scale;
                if (MODE == 0) {
                    const int t3 = grow >> 2, bb2 = grow & 3;
                    if (sel == 3) {   // vals (stream, BH, TM, NB), fp32
                        const int st = t3 >> 9, tm = t3 & 511;
                        const int nb = gcol >> 4, hh2 = gcol & 15;
                        ((float*)osel)[(((size_t)(st * BHH + bb2 * HH + hh2)) * TMQ + tm) * NBK + nb] = cval;
                    } else {
                        const int hh2 = gcol >> 6, d = gcol & 63;
                        __half* oh = (__half*)osel;
                        const __half hv = __float2half(cval);
                        if (sel == 2)  // V transposed: (BH, hd, T3)
                            oh[((size_t)((bb2 * HH + hh2) * HD + d)) * T3 + t3] = hv;
                        else           // Q, K: (BH, T3, hd)
                            oh[(((size_t)(bb2 * HH + hh2)) * T3 + t3) * HD + d] = hv;
                    }
                } else {
                    ((float*)osel)[(size_t)grow * EE + gcol] = cval;
                }
            }
        }
    }
}

// ---------------------------------------------------------------------------
// MFMA fused attention with register-prefetch pipeline (T14) + setprio (T5).
// Block = (stream s, head bh, 64 q-rows), 4 waves x 16 q-rows.
// Per 64-key chunk: ds_write prefetched K/Vt -> barrier -> issue next K/Vt
// loads -> QK^T (MFMA) -> gather+mask from prefetched idx/mask regs -> issue
// next idx/mask loads -> online softmax -> P (fp16, LDS) -> PV (MFMA).
// All global latencies hide under the previous chunk's compute.
// XCD mapping: each XCD gets 128 ngram + 64 main blocks (balanced 2560
// chunk-units/XCD), ngram (long) blocks dispatched first.
// ---------------------------------------------------------------------------
__global__ __launch_bounds__(256) void attn_mfma(
    const __half* __restrict__ q, const __half* __restrict__ k,
    const __half* __restrict__ vt, const float* __restrict__ vals,
    const float* __restrict__ self_mask, const float* __restrict__ ngram_mask,
    const int* __restrict__ ibm, const int* __restrict__ ibr,
    __half* __restrict__ attn_pre)
{
    __shared__ __half Qs [64 * 64];    // [q][d]    swizzled
    __shared__ __half Ks [64 * 64];    // [key][d]  swizzled
    __shared__ __half Vts[64 * 64];    // [d][key]  swizzled
    __shared__ __half Pa [64 * 64];    // [q][key]  swizzled (per-wave 16-row slice)
    __shared__ float  vals_s[64 * NBK];

    // balanced XCD mapping: xcd = bid&7; r<128 -> ngram, r>=128 -> main
    const int bid = blockIdx.x;
    const int xcd = bid & 7, rr = bid >> 3;
    int s, bh, qt;
    if (rr < 128) { const int g = xcd * 128 + rr; s = 1 + (g >> 9); bh = (g >> 3) & 63; qt = g & 7; }
    else          { const int mi = xcd * 64 + (rr - 128); s = 0; bh = mi >> 3; qt = mi & 7; }
    const int b = bh >> 4, h = bh & 15;
    const int tid = threadIdx.x;
    const int w = tid >> 6, lane = tid & 63;
    const int lc = lane & 15, lg = lane >> 4;
    const int nch = (s == 0) ? 8 : 16;

    // ---- stage Q (swizzled) + vals (linear) ----
    {
        const char* qg = (const char*)(q + ((size_t)bh * T3 + s * TMQ + qt * 64) * HD);
        const char* vg = (const char*)(vals + (((size_t)s * BHH + bh) * TMQ + qt * 64) * NBK);
        #pragma unroll
        for (int p = 0; p < 2; ++p) {
            const int u = tid + p * 256;
            const int row = u >> 3, sub = (u & 7) * 16;
            *(uint4*)((char*)Qs + row * 128 + SWZ(row, sub)) = *(const uint4*)(qg + (size_t)u * 16);
            *(uint4*)((char*)vals_s + (size_t)u * 16)         = *(const uint4*)(vg + (size_t)u * 16);
        }
    }

    // ---- prologue prefetch: chunk 0 K/Vt + idx/mask into registers ----
    uint4 ku0, ku1, vu0, vu1;
    int   ix[4][4];
    float mk[4][4];
    {
        const char* kg = (const char*)(k + (size_t)bh * T3 * HD);          // t3b(0)=0
        const char* vg = (const char*)(vt + (size_t)bh * HD * T3);
        ku0 = *(const uint4*)(kg + (size_t)tid * 16);
        ku1 = *(const uint4*)(kg + (size_t)(tid + 256) * 16);
        vu0 = *(const uint4*)(vg + (size_t)(tid >> 3) * (T3 * 2) + (tid & 7) * 16);
        vu1 = *(const uint4*)(vg + (size_t)((tid + 256) >> 3) * (T3 * 2) + (tid & 7) * 16);
        #pragma unroll
        for (int j = 0; j < 4; ++j) {
            const int t = qt * 64 + w * 16 + lg * 4 + j;
            const int* ip; const float* mp;
            if (s == 0) { ip = ibm + ((size_t)b * TMQ + t) * TMQ + lc;
                          mp = self_mask + (size_t)t * TMQ + lc; }
            else        { ip = ibr + ((size_t)b * TMQ + t) * (2 * TMQ) + lc;
                          mp = ngram_mask + ((size_t)(s - 1) * TMQ + t) * (2 * TMQ) + lc; }
            #pragma unroll
            for (int n = 0; n < 4; ++n) { ix[j][n] = ip[n * 16]; mk[j][n] = mp[n * 16]; }
        }
    }
    __syncthreads();   // Qs/vals_s staged

    // hoisted Q A-fragments (row = local q = w*16 + lc)
    half8 aq[2];
    {
        const int qr = w * 16 + lc;
        const char* qb = (const char*)Qs + qr * 128;
        aq[0] = *(const half8*)(qb + SWZ(qr, lg * 16));
        aq[1] = *(const half8*)(qb + SWZ(qr, 64 + lg * 16));
    }

    f32x4 o[4];
    #pragma unroll
    for (int nd = 0; nd < 4; ++nd) o[nd] = (f32x4){0.f, 0.f, 0.f, 0.f};
    float m_i[4], l_i[4];
    #pragma unroll
    for (int j = 0; j < 4; ++j) { m_i[j] = -1e30f; l_i[j] = 0.f; }

    for (int c = 0; c < nch; ++c) {
        // ---- ds_write prefetched K/Vt (vmcnt + prev-PV barrier ordering) ----
        if (c > 0) __syncthreads();   // all waves done reading Ks/Vts of c-1
        {
            const int u0 = tid, u1 = tid + 256;
            const int r0 = u0 >> 3, s0 = (u0 & 7) * 16;
            const int r1 = u1 >> 3, s1 = (u1 & 7) * 16;
            *(uint4*)((char*)Ks  + r0 * 128 + SWZ(r0, s0)) = ku0;
            *(uint4*)((char*)Ks  + r1 * 128 + SWZ(r1, s1)) = ku1;
            *(uint4*)((char*)Vts + r0 * 128 + SWZ(r0, s0)) = vu0;
            *(uint4*)((char*)Vts + r1 * 128 + SWZ(r1, s1)) = vu1;
        }
        __syncthreads();              // staged

        // ---- issue next chunk's K/Vt loads (hide under QK+softmax+PV) ----
        if (c + 1 < nch) {
            const int jn  = (c + 1) * 64;
            const int t3n = (jn < TMQ) ? jn : s * TMQ + (jn - TMQ);
            const char* kg = (const char*)(k + ((size_t)bh * T3 + t3n) * HD);
            const char* vg = (const char*)(vt + (size_t)bh * HD * T3 + t3n);
            ku0 = *(const uint4*)(kg + (size_t)tid * 16);
            ku1 = *(const uint4*)(kg + (size_t)(tid + 256) * 16);
            vu0 = *(const uint4*)(vg + (size_t)(tid >> 3) * (T3 * 2) + (tid & 7) * 16);
            vu1 = *(const uint4*)(vg + (size_t)((tid + 256) >> 3) * (T3 * 2) + (tid & 7) * 16);
        }

        // ---- QK^T: D[q_local][key] ----
        f32x4 sc[4];
        #pragma unroll
        for (int n = 0; n < 4; ++n) sc[n] = (f32x4){0.f, 0.f, 0.f, 0.f};
        __builtin_amdgcn_s_setprio(1);
        #pragma unroll
        for (int ks = 0; ks < 2; ++ks) {
            #pragma unroll
            for (int n = 0; n < 4; ++n) {
                const int kr = n * 16 + lc;
                const half8 bk = *(const half8*)((const char*)Ks + kr * 128 + SWZ(kr, ks * 64 + lg * 16));
                sc[n] = __builtin_amdgcn_mfma_f32_16x16x32_f16(aq[ks], bk, sc[n], 0, 0, 0);
            }
        }
        __builtin_amdgcn_s_setprio(0);

        // ---- E1: add bucket-gather + mask from prefetched regs ----
        #pragma unroll
        for (int j = 0; j < 4; ++j) {
            const int ql = w * 16 + lg * 4 + j;
            const float* vr = vals_s + ql * NBK;
            #pragma unroll
            for (int n = 0; n < 4; ++n)
                sc[n][j] += vr[ix[j][n]] + mk[j][n];
        }

        // ---- issue next chunk's idx/mask loads ----
        if (c + 1 < nch) {
            const int jn = (c + 1) * 64;
            #pragma unroll
            for (int j = 0; j < 4; ++j) {
                const int t = qt * 64 + w * 16 + lg * 4 + j;
                const int* ip; const float* mp;
                if (s == 0) { ip = ibm + ((size_t)b * TMQ + t) * TMQ + jn + lc;
                              mp = self_mask + (size_t)t * TMQ + jn + lc; }
                else        { ip = ibr + ((size_t)b * TMQ + t) * (2 * TMQ) + jn + lc;
                              mp = ngram_mask + ((size_t)(s - 1) * TMQ + t) * (2 * TMQ) + jn + lc; }
                #pragma unroll
                for (int n = 0; n < 4; ++n) { ix[j][n] = ip[n * 16]; mk[j][n] = mp[n * 16]; }
            }
        }

        // ---- E3: online softmax + P write (C-layout) ----
        #pragma unroll
        for (int j = 0; j < 4; ++j) {
            const int ql = w * 16 + lg * 4 + j;
            float rm = fmaxf(fmaxf(sc[0][j], sc[1][j]), fmaxf(sc[2][j], sc[3][j]));
            rm = fmaxf(rm, __shfl_xor(rm, 1));
            rm = fmaxf(rm, __shfl_xor(rm, 2));
            rm = fmaxf(rm, __shfl_xor(rm, 4));
            rm = fmaxf(rm, __shfl_xor(rm, 8));
            const float mn   = fmaxf(m_i[j], rm);
            const float corr = __expf(m_i[j] - mn);
            m_i[j] = mn;
            const float p0 = __expf(sc[0][j] - mn), p1 = __expf(sc[1][j] - mn);
            const float p2 = __expf(sc[2][j] - mn), p3 = __expf(sc[3][j] - mn);
            float rs = p0 + p1 + p2 + p3;
            rs += __shfl_xor(rs, 1);
            rs += __shfl_xor(rs, 2);
            rs += __shfl_xor(rs, 4);
            rs += __shfl_xor(rs, 8);
            l_i[j] = l_i[j] * corr + rs;
            #pragma unroll
            for (int nd = 0; nd < 4; ++nd) o[nd][j] *= corr;

            char* pb = (char*)Pa + ql * 128;
            *(__half*)(pb + SWZ(ql, (0 * 16 + lc) * 2)) = __float2half(p0);
            *(__half*)(pb + SWZ(ql, (1 * 16 + lc) * 2)) = __float2half(p1);
            *(__half*)(pb + SWZ(ql, (2 * 16 + lc) * 2)) = __float2half(p2);
            *(__half*)(pb + SWZ(ql, (3 * 16 + lc) * 2)) = __float2half(p3);
        }
        __threadfence_block();   // P-writes visible (Pa slice is per-wave)

        // ---- PV: O[q_local][d] += P[q][key] * Vt[d][key] ----
        __builtin_amdgcn_s_setprio(1);
        #pragma unroll
        for (int ks = 0; ks < 2; ++ks) {
            const int ar = w * 16 + lc;
            const half8 ap = *(const half8*)((const char*)Pa + ar * 128 + SWZ(ar, ks * 64 + lg * 16));
            #pragma unroll
            for (int nd = 0; nd < 4; ++nd) {
                const int vr2 = nd * 16 + lc;
                const half8 bv = *(const half8*)((const char*)Vts + vr2 * 128 + SWZ(vr2, ks * 64 + lg * 16));
                o[nd] = __builtin_amdgcn_mfma_f32_16x16x32_f16(ap, bv, o[nd], 0, 0, 0);
            }
        }
        __builtin_amdgcn_s_setprio(0);
    }

    // ---- normalize + write fp16 attn_pre (T3, B, E) ----
    #pragma unroll
    for (int j = 0; j < 4; ++j) {
        const float inv = 1.0f / l_i[j];
        const int t = qt * 64 + w * 16 + lg * 4 + j;
        __half* op = attn_pre + (((size_t)(s * TMQ + t)) * BB + b) * EE + h * HD + lc;
        #pragma unroll
        for (int nd = 0; nd < 4; ++nd)
            op[nd * 16] = __float2half(o[nd][j] * inv);
    }
}

// ---------------------------------------------------------------------------
// Launcher. Workspace: qh/kh/vth 12 MB each (fp16) | valsw 12 MB (fp32) |
// hs_h..Wr_h contiguous fp16 block (dst of cvt_all; hs_h aliased by apre_h)
// ---------------------------------------------------------------------------
extern "C" void kernel_launch(void* const* d_in, const int* in_sizes, int n_in,
                              void* d_out, int out_size, void* d_ws, size_t ws_size,
                              hipStream_t stream)
{
    const float* hs    = (const float*)d_in[0];
    const float* smask = (const float*)d_in[1];
    const float* nmask = (const float*)d_in[2];
    const int*   ibm   = (const int*)d_in[3];
    const int*   ibr   = (const int*)d_in[4];
    const float* Wq = (const float*)d_in[5];
    const float* bq = (const float*)d_in[6];
    const float* Wk = (const float*)d_in[7];
    const float* bk = (const float*)d_in[8];
    const float* Wv = (const float*)d_in[9];
    const float* bv = (const float*)d_in[10];
    const float* Wo = (const float*)d_in[11];
    const float* bo = (const float*)d_in[12];
    const float* Wr = (const float*)d_in[13];
    const float* br = (const float*)d_in[14];
    float* out = (float*)d_out;

    const size_t NQKV = (size_t)BHH * T3 * HD;   // 6,291,456
    __half* qh    = (__half*)d_ws;
    __half* kh    = qh + NQKV;
    __half* vth   = kh + NQKV;
    float*  valsw = (float*)(vth + NQKV);
    __half* hs_h  = (__half*)(valsw + (size_t)3 * BHH * TMQ * NBK);
    __half* apre_h = hs_h;                        // alias: hs_h dead before attn writes
    __half* Wq_h = hs_h + (size_t)T3 * BB * EE;   // contiguous with hs_h (cvt_all dst)
    __half* Wk_h = Wq_h + (size_t)EE * EE;
    __half* Wv_h = Wk_h + (size_t)EE * EE;
    __half* Wo_h = Wv_h + (size_t)EE * EE;
    __half* Wr_h = Wo_h + (size_t)EE * EE;

    dim3 blk(256);
    // all fp32 -> fp16 conversions in one launch (dst = hs_h..Wr_h contiguous)
    cvt_all<<<dim3(10752), blk, 0, stream>>>(hs, Wq, Wk, Wv, Wo, Wr, hs_h);

    // fused QKV + Wr projections (q,k -> (BH,T3,hd); v -> (BH,hd,T3); Wr -> vals)
    gemm16<0><<<dim3(28, 48), blk, 0, stream>>>(hs_h, Wq_h, Wk_h, Wv_h, Wr_h,
                                                bq, bk, bv, br,
                                                qh, kh, vth, valsw);
    // MFMA fused attention -> fp16 apre (hs_h now dead)
    attn_mfma<<<dim3(1536), blk, 0, stream>>>(qh, kh, vth, valsw, smask, nmask,
                                              ibm, ibr, apre_h);
    // output projection -> d_out (fp32)
    gemm16<2><<<dim3(8, 48), blk, 0, stream>>>(apre_h, Wo_h, nullptr, nullptr, nullptr,
                                               bo, nullptr, nullptr, nullptr,
                                               out, nullptr, nullptr, nullptr);
}